// Round 1
// baseline (2230.335 us; speedup 1.0000x reference)
//
#include <hip/hip_runtime.h>

// Problem constants
#define Bc   2
#define Sc   1024
#define Hc   2048
#define NHc  16
#define NKVc 4
#define HDc  128
#define KBc  1024
#define NREPc 4

static __device__ __forceinline__ size_t dsz(int x) { return (size_t)x; }

// ---------------------------------------------------------------------------
// Generic fp32 GEMM: C[M,N] = A[M,K] * B[N,K]^T   (both row-major)
// 64x64 tile, 256 threads, 4x4 per thread, K-step 16, LDS staged.
// M,N multiples of 64; K multiple of 16 (true for all calls here).
// ---------------------------------------------------------------------------
__global__ __launch_bounds__(256) void gemm_nt_f32(const float* __restrict__ A,
                                                   const float* __restrict__ Bm,
                                                   float* __restrict__ C,
                                                   int M, int N, int K)
{
  __shared__ float sA[16][68];   // [k][row], padded: row stride 68*4=272B (16B-aligned)
  __shared__ float sB[16][68];   // [k][col]
  const int tid = threadIdx.x;
  const int tx = tid & 15;       // col group
  const int ty = tid >> 4;       // row group
  const int row0 = blockIdx.y * 64;
  const int col0 = blockIdx.x * 64;

  float acc[4][4];
  #pragma unroll
  for (int i = 0; i < 4; ++i)
    #pragma unroll
    for (int j = 0; j < 4; ++j) acc[i][j] = 0.f;

  for (int k0 = 0; k0 < K; k0 += 16) {
    #pragma unroll
    for (int i = 0; i < 4; ++i) {
      int idx = tid + i * 256;          // 0..1023
      int r  = idx >> 4;                // 0..63
      int kk = idx & 15;                // 0..15
      sA[kk][r] = A [dsz(row0 + r) * K + k0 + kk];
      sB[kk][r] = Bm[dsz(col0 + r) * K + k0 + kk];
    }
    __syncthreads();
    #pragma unroll
    for (int kk = 0; kk < 16; ++kk) {
      float4 a4 = *(const float4*)&sA[kk][ty * 4];
      float4 b4 = *(const float4*)&sB[kk][tx * 4];
      float av[4] = {a4.x, a4.y, a4.z, a4.w};
      float bv[4] = {b4.x, b4.y, b4.z, b4.w};
      #pragma unroll
      for (int i = 0; i < 4; ++i)
        #pragma unroll
        for (int j = 0; j < 4; ++j)
          acc[i][j] += av[i] * bv[j];
    }
    __syncthreads();
  }

  #pragma unroll
  for (int i = 0; i < 4; ++i)
    #pragma unroll
    for (int j = 0; j < 4; ++j)
      C[dsz(row0 + ty * 4 + i) * N + col0 + tx * 4 + j] = acc[i][j];
}

// ---------------------------------------------------------------------------
// RoPE in-place on a (rows, nheads*128) tensor. One thread per (row, head, j<64)
// pair: rotates dims (j, j+64).
// inv_freq[j] = 10000^(-j/64) = exp(-j * ln(10000)/64)
// ---------------------------------------------------------------------------
__global__ void rope_f32(float* __restrict__ x, const int* __restrict__ pos_ids,
                         int rows, int nheads)
{
  int idx = blockIdx.x * blockDim.x + threadIdx.x;
  int total = rows * nheads * 64;
  if (idx >= total) return;
  int j = idx & 63;
  int h = (idx >> 6) % nheads;
  int r = idx / (64 * nheads);
  float pos = (float)pos_ids[r];
  float inv = expf(-(float)j * 0.14391156831212787f);  // ln(10000)/64
  float f = pos * inv;
  float c = cosf(f);
  float s = sinf(f);
  float* base = x + dsz(r) * (nheads * 128) + h * 128;
  float x1 = base[j];
  float x2 = base[j + 64];
  base[j]      = x1 * c - x2 * s;
  base[j + 64] = x2 * c + x1 * s;
}

// ---------------------------------------------------------------------------
// Attention (online softmax, two phases: KB keys with q_new, self keys with q).
// Block: one (b, h, tile of 32 queries). 256 threads = 32 queries x 8 dim-groups
// (each dim-group owns 16 of the 128 head dims). K/V staged in LDS, 32 keys/chunk.
// ---------------------------------------------------------------------------
__global__ __launch_bounds__(256) void attn_f32(
    const float* __restrict__ q,      // (B*S, NH*HD), roped
    const float* __restrict__ qn,     // (B*S, NH*HD), raw (q_new)
    const float* __restrict__ kself,  // (B*S, NKV*HD), roped
    const float* __restrict__ vself,  // (B*S, NKV*HD)
    const float* __restrict__ kbk,    // (B, KB, NKV*HD)
    const float* __restrict__ kbv,    // (B, KB, NKV*HD)
    float* __restrict__ attn_out)     // (B*S, NH*HD)
{
  __shared__ float sK[32][132];
  __shared__ float sV[32][132];

  const int blk = blockIdx.x;
  const int qt = blk & (Sc / 32 - 1);          // 0..31
  const int h  = (blk >> 5) & (NHc - 1);       // 0..15
  const int b  = blk >> 9;                     // 0..1
  const int kvh = h / NREPc;

  const int tid = threadIdx.x;
  const int qi = tid >> 3;   // 0..31
  const int di = tid & 7;    // 0..7
  const int qrow = qt * 32 + qi;               // s index of this thread's query

  const size_t qbase = dsz(b * Sc + qrow) * (NHc * HDc) + h * HDc + di * 16;
  const float SCALE = 0.08838834764831845f;    // 1/sqrt(128)

  float m = -1e30f, l = 0.f;
  float o[16];
  #pragma unroll
  for (int j = 0; j < 16; ++j) o[j] = 0.f;

  float qf[16];

  for (int phase = 0; phase < 2; ++phase) {
    const float* qptr = phase ? q : qn;
    #pragma unroll
    for (int j = 0; j < 16; ++j) qf[j] = qptr[qbase + j];

    const float* Kg = phase ? kself + dsz(b) * Sc  * (NKVc * HDc) + kvh * HDc
                            : kbk   + dsz(b) * KBc * (NKVc * HDc) + kvh * HDc;
    const float* Vg = phase ? vself + dsz(b) * Sc  * (NKVc * HDc) + kvh * HDc
                            : kbv   + dsz(b) * KBc * (NKVc * HDc) + kvh * HDc;
    const int nk = phase ? Sc : KBc;   // both 1024

    for (int k0 = 0; k0 < nk; k0 += 32) {
      __syncthreads();   // protect LDS reuse from previous chunk
      #pragma unroll
      for (int t = 0; t < 4; ++t) {
        int idx = tid + t * 256;       // float4 index, 0..1023
        int r  = idx >> 5;             // key row in chunk, 0..31
        int c4 = idx & 31;             // float4 column, 0..31
        float4 k4 = *(const float4*)(Kg + dsz(k0 + r) * (NKVc * HDc) + c4 * 4);
        float4 v4 = *(const float4*)(Vg + dsz(k0 + r) * (NKVc * HDc) + c4 * 4);
        *(float4*)&sK[r][c4 * 4] = k4;
        *(float4*)&sV[r][c4 * 4] = v4;
      }
      __syncthreads();

      for (int kk = 0; kk < 32; ++kk) {
        const int ks = k0 + kk;
        float part = 0.f;
        #pragma unroll
        for (int j = 0; j < 16; ++j) part += qf[j] * sK[kk][di * 16 + j];
        part += __shfl_xor(part, 1);
        part += __shfl_xor(part, 2);
        part += __shfl_xor(part, 4);
        float score = part * SCALE;
        if (phase == 1 && ks > qrow) score = -1e9f;   // causal mask (== input mask)

        if (score > m) {
          float corr = __expf(m - score);
          m = score;
          l *= corr;
          #pragma unroll
          for (int j = 0; j < 16; ++j) o[j] *= corr;
        }
        float p = __expf(score - m);
        l += p;
        #pragma unroll
        for (int j = 0; j < 16; ++j) o[j] += p * sV[kk][di * 16 + j];
      }
    }
  }

  const float inv_l = 1.f / l;
  #pragma unroll
  for (int j = 0; j < 16; ++j) attn_out[qbase + j] = o[j] * inv_l;
}

// ---------------------------------------------------------------------------
// Launch
// ---------------------------------------------------------------------------
extern "C" void kernel_launch(void* const* d_in, const int* in_sizes, int n_in,
                              void* d_out, int out_size, void* d_ws, size_t ws_size,
                              hipStream_t stream)
{
  const float* x   = (const float*)d_in[0];
  // d_in[1] = attention_mask: exactly the causal 0/-1e9 mask; recomputed inline.
  const int*   pos = (const int*)d_in[2];
  const float* kbk = (const float*)d_in[3];
  const float* kbv = (const float*)d_in[4];
  const float* Wq  = (const float*)d_in[5];
  const float* Wqn = (const float*)d_in[6];
  const float* Wk  = (const float*)d_in[7];
  const float* Wv  = (const float*)d_in[8];
  const float* Wo  = (const float*)d_in[9];
  float* out = (float*)d_out;

  const int MR = Bc * Sc;              // 2048 rows
  float* ws   = (float*)d_ws;
  float* q    = ws;                                   // MR*2048
  float* qn   = q    + (size_t)MR * 2048;             // MR*2048
  float* kkv  = qn   + (size_t)MR * 2048;             // MR*512
  float* vkv  = kkv  + (size_t)MR * 512;              // MR*512
  float* attn = vkv  + (size_t)MR * 512;              // MR*2048
  // total: 14,680,064 floats = 58.7 MB of d_ws

  dim3 blk(256);
  // Projections: C = x * W^T
  gemm_nt_f32<<<dim3(2048 / 64, MR / 64), blk, 0, stream>>>(x, Wq,  q,   MR, 2048, Hc);
  gemm_nt_f32<<<dim3(2048 / 64, MR / 64), blk, 0, stream>>>(x, Wqn, qn,  MR, 2048, Hc);
  gemm_nt_f32<<<dim3(512  / 64, MR / 64), blk, 0, stream>>>(x, Wk,  kkv, MR, 512,  Hc);
  gemm_nt_f32<<<dim3(512  / 64, MR / 64), blk, 0, stream>>>(x, Wv,  vkv, MR, 512,  Hc);

  // RoPE on q (16 heads) and self-k (4 heads); q_new stays raw.
  rope_f32<<<(MR * NHc  * 64 + 255) / 256, 256, 0, stream>>>(q,   pos, MR, NHc);
  rope_f32<<<(MR * NKVc * 64 + 255) / 256, 256, 0, stream>>>(kkv, pos, MR, NKVc);

  // Attention: B*NH*(S/32) = 1024 blocks.
  attn_f32<<<dim3(Bc * NHc * (Sc / 32)), blk, 0, stream>>>(q, qn, kkv, vkv, kbk, kbv, attn);

  // Output projection: out = attn * Wo^T
  gemm_nt_f32<<<dim3(2048 / 64, MR / 64), blk, 0, stream>>>(attn, Wo, out, MR, 2048, Hc);
}

// Round 2
// 1577.393 us; speedup vs baseline: 1.4139x; 1.4139x over previous
//
#include <hip/hip_runtime.h>

// Problem constants
#define Bc   2
#define Sc   1024
#define Hc   2048
#define NHc  16
#define NKVc 4
#define HDc  128
#define KBc  1024
#define NREPc 4

typedef unsigned short ushort_t;
typedef unsigned int uint32;
typedef __attribute__((ext_vector_type(8))) __bf16 bf16x8;
typedef __attribute__((ext_vector_type(4))) float f32x4;

static __device__ __forceinline__ size_t dsz(int x) { return (size_t)x; }

static __device__ __forceinline__ ushort_t f2bf(float f) {
  uint32 u = __float_as_uint(f);
  u += 0x7fffu + ((u >> 16) & 1u);        // round-to-nearest-even
  return (ushort_t)(u >> 16);
}

// ---------------------------------------------------------------------------
// fp32 -> bf16 conversion (vectorized, n must be multiple of 4 — true here)
// ---------------------------------------------------------------------------
__global__ void f32_to_bf16(const float* __restrict__ src,
                            ushort_t* __restrict__ dst, int n4)
{
  int i = blockIdx.x * blockDim.x + threadIdx.x;
  if (i >= n4) return;
  float4 v = ((const float4*)src)[i];
  ushort4 o;
  o.x = f2bf(v.x); o.y = f2bf(v.y); o.z = f2bf(v.z); o.w = f2bf(v.w);
  ((ushort4*)dst)[i] = o;
}

// ---------------------------------------------------------------------------
// bf16 MFMA GEMM (m97 structure): C[M,N] = A[M,K] * B[N,K]^T, fp32 out.
// 128x128 tile, 256 thr = 4 waves (2x2), BK=32, global_load_lds w16,
// mfma_f32_16x16x32_bf16. M,N mult of 128; K mult of 32; K*2 row bytes 16B-mult.
// ---------------------------------------------------------------------------
#define GL16(gsrc, ldst)                                                \
  __builtin_amdgcn_global_load_lds(                                     \
      (const __attribute__((address_space(1))) void*)(gsrc),            \
      (__attribute__((address_space(3))) void*)(ldst), 16, 0, 0)

__global__ __launch_bounds__(256) void gemm_bt_bf16(
    const ushort_t* __restrict__ A,   // [M][K] bf16 bits
    const ushort_t* __restrict__ B,   // [N][K] bf16 bits
    float* __restrict__ C,            // [M][N]
    int M, int N, int K)
{
  __shared__ ushort_t sA[128 * 32];
  __shared__ ushort_t sB[128 * 32];

  const int tid  = threadIdx.x;
  const int lane = tid & 63;
  const int wid  = tid >> 6;
  const int wr   = wid >> 1;          // wave row (0/1)
  const int wc   = wid & 1;           // wave col (0/1)
  const int row0 = blockIdx.y * 128;
  const int col0 = blockIdx.x * 128;

  const int fr = lane & 15;           // fragment row (A) / col (B) / col (C)
  const int fq = lane >> 4;           // 0..3

  f32x4 acc[4][4];
  #pragma unroll
  for (int m = 0; m < 4; ++m)
    #pragma unroll
    for (int n = 0; n < 4; ++n) acc[m][n] = (f32x4){0.f, 0.f, 0.f, 0.f};

  // staging geometry: thread t covers LDS bytes t*16 (+4096 for second half)
  const int rS = tid >> 2;            // tile row 0..63 (first half)
  const int kg = (tid & 3) * 8;       // k element offset (16B)
  const ushort_t* Asrc0 = A + dsz(row0 + rS) * K + kg;
  const ushort_t* Asrc1 = A + dsz(row0 + 64 + rS) * K + kg;
  const ushort_t* Bsrc0 = B + dsz(col0 + rS) * K + kg;
  const ushort_t* Bsrc1 = B + dsz(col0 + 64 + rS) * K + kg;
  char* ldsA0 = (char*)sA + tid * 16;
  char* ldsA1 = (char*)sA + 4096 + tid * 16;
  char* ldsB0 = (char*)sB + tid * 16;
  char* ldsB1 = (char*)sB + 4096 + tid * 16;

  for (int k0 = 0; k0 < K; k0 += 32) {
    GL16(Asrc0 + k0, ldsA0);
    GL16(Asrc1 + k0, ldsA1);
    GL16(Bsrc0 + k0, ldsB0);
    GL16(Bsrc1 + k0, ldsB1);
    __syncthreads();

    bf16x8 a[4], b[4];
    #pragma unroll
    for (int m = 0; m < 4; ++m)
      a[m] = *(const bf16x8*)&sA[(wr * 64 + m * 16 + fr) * 32 + fq * 8];
    #pragma unroll
    for (int n = 0; n < 4; ++n)
      b[n] = *(const bf16x8*)&sB[(wc * 64 + n * 16 + fr) * 32 + fq * 8];
    #pragma unroll
    for (int m = 0; m < 4; ++m)
      #pragma unroll
      for (int n = 0; n < 4; ++n)
        acc[m][n] = __builtin_amdgcn_mfma_f32_16x16x32_bf16(a[m], b[n], acc[m][n], 0, 0, 0);
    __syncthreads();
  }

  // C/D layout (m89 verified): col = lane&15, row = (lane>>4)*4 + reg
  #pragma unroll
  for (int m = 0; m < 4; ++m)
    #pragma unroll
    for (int n = 0; n < 4; ++n)
      #pragma unroll
      for (int j = 0; j < 4; ++j)
        C[dsz(row0 + wr * 64 + m * 16 + fq * 4 + j) * N +
          col0 + wc * 64 + n * 16 + fr] = acc[m][n][j];
}

// ---------------------------------------------------------------------------
// RoPE in-place on a (rows, nheads*128) fp32 tensor.
// ---------------------------------------------------------------------------
__global__ void rope_f32(float* __restrict__ x, const int* __restrict__ pos_ids,
                         int rows, int nheads)
{
  int idx = blockIdx.x * blockDim.x + threadIdx.x;
  int total = rows * nheads * 64;
  if (idx >= total) return;
  int j = idx & 63;
  int h = (idx >> 6) % nheads;
  int r = idx / (64 * nheads);
  float pos = (float)pos_ids[r];
  float inv = expf(-(float)j * 0.14391156831212787f);  // ln(10000)/64
  float f = pos * inv;
  float c = cosf(f);
  float s = sinf(f);
  float* base = x + dsz(r) * (nheads * 128) + h * 128;
  float x1 = base[j];
  float x2 = base[j + 64];
  base[j]      = x1 * c - x2 * s;
  base[j + 64] = x2 * c + x1 * s;
}

// ---------------------------------------------------------------------------
// Attention (online softmax, phase 0: KB keys w/ q_new, phase 1: causal self).
// Block = (b, h, 32 queries); 256 thr = 32 q x 8 dim-groups.
// Dim ownership INTERLEAVED: thread di owns dims {j*8+di} -> conflict-free LDS.
// Output written directly as bf16 (feeds Wo MFMA GEMM).
// ---------------------------------------------------------------------------
__global__ __launch_bounds__(256) void attn_f32(
    const float* __restrict__ q,      // (B*S, NH*HD), roped
    const float* __restrict__ qn,     // (B*S, NH*HD), raw (q_new)
    const float* __restrict__ kself,  // (B*S, NKV*HD), roped
    const float* __restrict__ vself,  // (B*S, NKV*HD)
    const float* __restrict__ kbk,    // (B, KB, NKV*HD)
    const float* __restrict__ kbv,    // (B, KB, NKV*HD)
    ushort_t* __restrict__ attn_out)  // (B*S, NH*HD) bf16
{
  __shared__ float sK[32][132];
  __shared__ float sV[32][132];

  const int blk = blockIdx.x;
  const int qt = blk & (Sc / 32 - 1);
  const int h  = (blk >> 5) & (NHc - 1);
  const int b  = blk >> 9;
  const int kvh = h / NREPc;

  const int tid = threadIdx.x;
  const int qi = tid >> 3;   // 0..31
  const int di = tid & 7;    // 0..7
  const int qrow = qt * 32 + qi;

  const size_t qbase = dsz(b * Sc + qrow) * (NHc * HDc) + h * HDc;
  const float SCALE = 0.08838834764831845f;    // 1/sqrt(128)

  float m = -1e30f, l = 0.f;
  float o[16];
  #pragma unroll
  for (int j = 0; j < 16; ++j) o[j] = 0.f;

  float qf[16];

  for (int phase = 0; phase < 2; ++phase) {
    const float* qptr = phase ? q : qn;
    #pragma unroll
    for (int j = 0; j < 16; ++j) qf[j] = qptr[qbase + j * 8 + di];

    const float* Kg = phase ? kself + dsz(b) * Sc  * (NKVc * HDc) + kvh * HDc
                            : kbk   + dsz(b) * KBc * (NKVc * HDc) + kvh * HDc;
    const float* Vg = phase ? vself + dsz(b) * Sc  * (NKVc * HDc) + kvh * HDc
                            : kbv   + dsz(b) * KBc * (NKVc * HDc) + kvh * HDc;
    const int nk = phase ? Sc : KBc;

    for (int k0 = 0; k0 < nk; k0 += 32) {
      __syncthreads();
      #pragma unroll
      for (int t = 0; t < 4; ++t) {
        int idx = tid + t * 256;
        int r  = idx >> 5;
        int c4 = idx & 31;
        float4 k4 = *(const float4*)(Kg + dsz(k0 + r) * (NKVc * HDc) + c4 * 4);
        float4 v4 = *(const float4*)(Vg + dsz(k0 + r) * (NKVc * HDc) + c4 * 4);
        *(float4*)&sK[r][c4 * 4] = k4;
        *(float4*)&sV[r][c4 * 4] = v4;
      }
      __syncthreads();

      for (int kk = 0; kk < 32; ++kk) {
        const int ks = k0 + kk;
        float part = 0.f;
        #pragma unroll
        for (int j = 0; j < 16; ++j) part += qf[j] * sK[kk][j * 8 + di];
        part += __shfl_xor(part, 1);
        part += __shfl_xor(part, 2);
        part += __shfl_xor(part, 4);
        float score = part * SCALE;
        if (phase == 1 && ks > qrow) score = -1e9f;

        if (score > m) {
          float corr = __expf(m - score);
          m = score;
          l *= corr;
          #pragma unroll
          for (int j = 0; j < 16; ++j) o[j] *= corr;
        }
        float p = __expf(score - m);
        l += p;
        #pragma unroll
        for (int j = 0; j < 16; ++j) o[j] += p * sV[kk][j * 8 + di];
      }
    }
  }

  const float inv_l = 1.f / l;
  #pragma unroll
  for (int j = 0; j < 16; ++j)
    attn_out[qbase + j * 8 + di] = f2bf(o[j] * inv_l);
}

// ---------------------------------------------------------------------------
// Launch
// ---------------------------------------------------------------------------
extern "C" void kernel_launch(void* const* d_in, const int* in_sizes, int n_in,
                              void* d_out, int out_size, void* d_ws, size_t ws_size,
                              hipStream_t stream)
{
  const float* x   = (const float*)d_in[0];
  const int*   pos = (const int*)d_in[2];
  const float* kbk = (const float*)d_in[3];
  const float* kbv = (const float*)d_in[4];
  const float* Wq  = (const float*)d_in[5];
  const float* Wqn = (const float*)d_in[6];
  const float* Wk  = (const float*)d_in[7];
  const float* Wv  = (const float*)d_in[8];
  const float* Wo  = (const float*)d_in[9];
  float* out = (float*)d_out;

  const int MR = Bc * Sc;              // 2048 rows
  const size_t M4 = (size_t)MR * 2048; // 4M
  const size_t M1 = (size_t)MR * 512;  // 1M

  // fp32 intermediates
  float* ws  = (float*)d_ws;
  float* q   = ws;               // 4M f
  float* qn  = q   + M4;         // 4M f
  float* kkv = qn  + M4;         // 1M f
  float* vkv = kkv + M1;         // 1M f
  // bf16 region
  ushort_t* bfbase = (ushort_t*)(vkv + M1);
  ushort_t* xb   = bfbase;             // 4M  (later reused as attnb)
  ushort_t* Wqb  = xb   + M4;          // 4M
  ushort_t* Wqnb = Wqb  + M4;          // 4M
  ushort_t* Wkb  = Wqnb + M4;          // 1M
  ushort_t* Wvb  = Wkb  + M1;          // 1M
  ushort_t* Wob  = Wvb  + M1;          // 4M
  ushort_t* attnb = xb;                // alias: x-GEMMs all precede attention
  // total ws: 10M*4 + 18M*2 = 77.6 MB

  dim3 blk(256);
  // fp32 -> bf16 conversions
  f32_to_bf16<<<(int)(M4 / 4 / 256), blk, 0, stream>>>(x,   xb,   (int)(M4 / 4));
  f32_to_bf16<<<(int)(M4 / 4 / 256), blk, 0, stream>>>(Wq,  Wqb,  (int)(M4 / 4));
  f32_to_bf16<<<(int)(M4 / 4 / 256), blk, 0, stream>>>(Wqn, Wqnb, (int)(M4 / 4));
  f32_to_bf16<<<(int)(M1 / 4 / 256), blk, 0, stream>>>(Wk,  Wkb,  (int)(M1 / 4));
  f32_to_bf16<<<(int)(M1 / 4 / 256), blk, 0, stream>>>(Wv,  Wvb,  (int)(M1 / 4));
  f32_to_bf16<<<(int)(M4 / 4 / 256), blk, 0, stream>>>(Wo,  Wob,  (int)(M4 / 4));

  // Projections (bf16 MFMA): C = x * W^T
  gemm_bt_bf16<<<dim3(16, 16), blk, 0, stream>>>(xb, Wqb,  q,   MR, 2048, Hc);
  gemm_bt_bf16<<<dim3(16, 16), blk, 0, stream>>>(xb, Wqnb, qn,  MR, 2048, Hc);
  gemm_bt_bf16<<<dim3(4,  16), blk, 0, stream>>>(xb, Wkb,  kkv, MR, 512,  Hc);
  gemm_bt_bf16<<<dim3(4,  16), blk, 0, stream>>>(xb, Wvb,  vkv, MR, 512,  Hc);

  // RoPE on q (16 heads) and self-k (4 heads)
  rope_f32<<<(MR * NHc  * 64 + 255) / 256, 256, 0, stream>>>(q,   pos, MR, NHc);
  rope_f32<<<(MR * NKVc * 64 + 255) / 256, 256, 0, stream>>>(kkv, pos, MR, NKVc);

  // Attention -> bf16 attnb (aliases xb; all xb readers are done by now)
  attn_f32<<<dim3(Bc * NHc * (Sc / 32)), blk, 0, stream>>>(q, qn, kkv, vkv, kbk, kbv, attnb);

  // Output projection: out = attn * Wo^T
  gemm_bt_bf16<<<dim3(16, 16), blk, 0, stream>>>(attnb, Wob, out, MR, 2048, Hc);
}

// Round 3
// 505.936 us; speedup vs baseline: 4.4083x; 3.1178x over previous
//
#include <hip/hip_runtime.h>

// Problem constants
#define Bc   2
#define Sc   1024
#define Hc   2048
#define NHc  16
#define NKVc 4
#define HDc  128
#define KBc  1024
#define NREPc 4

typedef unsigned short ushort_t;
typedef unsigned int uint32;
typedef __attribute__((ext_vector_type(8))) __bf16 bf16x8;
typedef __attribute__((ext_vector_type(4))) float f32x4;

static __device__ __forceinline__ size_t dsz(int x) { return (size_t)x; }

static __device__ __forceinline__ ushort_t f2bf(float f) {
  uint32 u = __float_as_uint(f);
  u += 0x7fffu + ((u >> 16) & 1u);        // round-to-nearest-even
  return (ushort_t)(u >> 16);
}

// ---------------------------------------------------------------------------
// fp32 -> bf16 conversion (n4 float4s)
// ---------------------------------------------------------------------------
__global__ void f32_to_bf16(const float* __restrict__ src,
                            ushort_t* __restrict__ dst, int n4)
{
  int i = blockIdx.x * blockDim.x + threadIdx.x;
  if (i >= n4) return;
  float4 v = ((const float4*)src)[i];
  ushort4 o;
  o.x = f2bf(v.x); o.y = f2bf(v.y); o.z = f2bf(v.z); o.w = f2bf(v.w);
  ((ushort4*)dst)[i] = o;
}

// scaled variant (for q_new pre-scaling)
__global__ void f32_to_bf16_s(const float* __restrict__ src,
                              ushort_t* __restrict__ dst, int n4, float scale)
{
  int i = blockIdx.x * blockDim.x + threadIdx.x;
  if (i >= n4) return;
  float4 v = ((const float4*)src)[i];
  ushort4 o;
  o.x = f2bf(v.x * scale); o.y = f2bf(v.y * scale);
  o.z = f2bf(v.z * scale); o.w = f2bf(v.w * scale);
  ((ushort4*)dst)[i] = o;
}

// ---------------------------------------------------------------------------
// bf16 MFMA GEMM (m97 structure): C[M,N] = A[M,K] * B[N,K]^T, fp32 out.
// ---------------------------------------------------------------------------
#define GL16(gsrc, ldst)                                                \
  __builtin_amdgcn_global_load_lds(                                     \
      (const __attribute__((address_space(1))) void*)(gsrc),            \
      (__attribute__((address_space(3))) void*)(ldst), 16, 0, 0)

__global__ __launch_bounds__(256) void gemm_bt_bf16(
    const ushort_t* __restrict__ A,   // [M][K] bf16 bits
    const ushort_t* __restrict__ B,   // [N][K] bf16 bits
    float* __restrict__ C,            // [M][N]
    int M, int N, int K)
{
  __shared__ ushort_t sA[128 * 32];
  __shared__ ushort_t sB[128 * 32];

  const int tid  = threadIdx.x;
  const int lane = tid & 63;
  const int wid  = tid >> 6;
  const int wr   = wid >> 1;
  const int wc   = wid & 1;
  const int row0 = blockIdx.y * 128;
  const int col0 = blockIdx.x * 128;

  const int fr = lane & 15;
  const int fq = lane >> 4;

  f32x4 acc[4][4];
  #pragma unroll
  for (int m = 0; m < 4; ++m)
    #pragma unroll
    for (int n = 0; n < 4; ++n) acc[m][n] = (f32x4){0.f, 0.f, 0.f, 0.f};

  const int rS = tid >> 2;
  const int kg = (tid & 3) * 8;
  const ushort_t* Asrc0 = A + dsz(row0 + rS) * K + kg;
  const ushort_t* Asrc1 = A + dsz(row0 + 64 + rS) * K + kg;
  const ushort_t* Bsrc0 = B + dsz(col0 + rS) * K + kg;
  const ushort_t* Bsrc1 = B + dsz(col0 + 64 + rS) * K + kg;
  char* ldsA0 = (char*)sA + tid * 16;
  char* ldsA1 = (char*)sA + 4096 + tid * 16;
  char* ldsB0 = (char*)sB + tid * 16;
  char* ldsB1 = (char*)sB + 4096 + tid * 16;

  for (int k0 = 0; k0 < K; k0 += 32) {
    GL16(Asrc0 + k0, ldsA0);
    GL16(Asrc1 + k0, ldsA1);
    GL16(Bsrc0 + k0, ldsB0);
    GL16(Bsrc1 + k0, ldsB1);
    __syncthreads();

    bf16x8 a[4], b[4];
    #pragma unroll
    for (int m = 0; m < 4; ++m)
      a[m] = *(const bf16x8*)&sA[(wr * 64 + m * 16 + fr) * 32 + fq * 8];
    #pragma unroll
    for (int n = 0; n < 4; ++n)
      b[n] = *(const bf16x8*)&sB[(wc * 64 + n * 16 + fr) * 32 + fq * 8];
    #pragma unroll
    for (int m = 0; m < 4; ++m)
      #pragma unroll
      for (int n = 0; n < 4; ++n)
        acc[m][n] = __builtin_amdgcn_mfma_f32_16x16x32_bf16(a[m], b[n], acc[m][n], 0, 0, 0);
    __syncthreads();
  }

  #pragma unroll
  for (int m = 0; m < 4; ++m)
    #pragma unroll
    for (int n = 0; n < 4; ++n)
      #pragma unroll
      for (int j = 0; j < 4; ++j)
        C[dsz(row0 + wr * 64 + m * 16 + fq * 4 + j) * N +
          col0 + wc * 64 + n * 16 + fr] = acc[m][n][j];
}

// ---------------------------------------------------------------------------
// RoPE q -> bf16 pre-scaled by SCALE*log2(e)  (for exp2-domain softmax)
// ---------------------------------------------------------------------------
#define ROPE_INV 0.14391156831212787f   // ln(10000)/64
#define QSCALE   (0.08838834764831845f * 1.4426950408889634f)

__global__ void rope_q_bf16(const float* __restrict__ q, const int* __restrict__ pos,
                            ushort_t* __restrict__ out)   // (B*S, NH*128)
{
  int idx = blockIdx.x * blockDim.x + threadIdx.x;   // 2M threads
  int j = idx & 63;
  int h = (idx >> 6) & 15;
  int r = idx >> 10;                                 // 0..2047
  float p = (float)pos[r];
  float f = p * expf(-(float)j * ROPE_INV);
  float c = cosf(f);
  float s = sinf(f);
  const float* src = q + dsz(r) * (NHc * HDc) + h * HDc;
  ushort_t* dst = out + dsz(r) * (NHc * HDc) + h * HDc;
  float x1 = src[j], x2 = src[j + 64];
  dst[j]      = f2bf((x1 * c - x2 * s) * QSCALE);
  dst[j + 64] = f2bf((x2 * c + x1 * s) * QSCALE);
}

// RoPE self-k -> Kcat rows 1024..2047 (no scale)
__global__ void rope_k_kcat(const float* __restrict__ kkv, const int* __restrict__ pos,
                            ushort_t* __restrict__ Kcat)
{
  int idx = blockIdx.x * blockDim.x + threadIdx.x;   // 512K threads
  int j = idx & 63;
  int kvh = (idx >> 6) & 3;
  int s = (idx >> 8) & 1023;
  int b = idx >> 18;
  float p = (float)pos[b * Sc + s];
  float f = p * expf(-(float)j * ROPE_INV);
  float c = cosf(f);
  float sn = sinf(f);
  const float* src = kkv + dsz(b * Sc + s) * (NKVc * HDc) + kvh * HDc;
  ushort_t* dst = Kcat + (dsz(b * NKVc + kvh) * 2048 + 1024 + s) * HDc;
  float x1 = src[j], x2 = src[j + 64];
  dst[j]      = f2bf(x1 * c - x2 * sn);
  dst[j + 64] = f2bf(x2 * c + x1 * sn);
}

// kb_keys (B,KB,NKV*HD) fp32 -> Kcat rows 0..1023 bf16
__global__ void kb_kcat(const float* __restrict__ src, ushort_t* __restrict__ Kcat)
{
  int i = blockIdx.x * blockDim.x + threadIdx.x;     // 262144
  int d4 = i & 31;
  int kvh = (i >> 5) & 3;
  int k = (i >> 7) & 1023;
  int b = i >> 17;
  float4 v = *(const float4*)&src[dsz(b * KBc + k) * (NKVc * HDc) + kvh * HDc + d4 * 4];
  ushort4 o;
  o.x = f2bf(v.x); o.y = f2bf(v.y); o.z = f2bf(v.z); o.w = f2bf(v.w);
  *(ushort4*)&Kcat[(dsz(b * NKVc + kvh) * 2048 + k) * HDc + d4 * 4] = o;
}

// Build Vt[b][kvh][128][2048] bf16 from kb_values (cols 0..1023) + vkv (1024..2047)
__global__ __launch_bounds__(256) void vt_build(const float* __restrict__ kbv,
                                                const float* __restrict__ vkv,
                                                ushort_t* __restrict__ Vt)
{
  __shared__ float sT[32][33];
  const int k0 = blockIdx.x * 32;      // 0..2047
  const int d0 = blockIdx.y * 32;      // 0..127
  const int bk = blockIdx.z;           // b*4+kvh
  const int b = bk >> 2, kvh = bk & 3;
  const int tid = threadIdx.x;

  #pragma unroll
  for (int t = 0; t < 4; ++t) {
    int li = tid + t * 256;
    int kk = li >> 5, dl = li & 31;
    int kg = k0 + kk;
    float v = (kg < 1024)
      ? kbv[dsz(b * KBc + kg) * (NKVc * HDc) + kvh * HDc + d0 + dl]
      : vkv[dsz(b * Sc + kg - 1024) * (NKVc * HDc) + kvh * HDc + d0 + dl];
    sT[kk][dl] = v;
  }
  __syncthreads();
  #pragma unroll
  for (int t = 0; t < 4; ++t) {
    int li = tid + t * 256;
    int dl = li >> 5, kk = li & 31;
    Vt[(dsz(b * NKVc + kvh) * HDc + d0 + dl) * 2048 + k0 + kk] = f2bf(sT[kk][dl]);
  }
}

// ---------------------------------------------------------------------------
// MFMA flash attention, no LDS. Block = (b, h, 64 queries), 4 waves x 16 rows.
// Swapped QK^T (S^T = mfma(K,Q)) with PERMUTED K rows so P lands directly in
// the PV B-operand layout (zero P shuffles). Online softmax in exp2 domain.
// ---------------------------------------------------------------------------
__global__ __launch_bounds__(256) void attn_mfma(
    const ushort_t* __restrict__ Qr,   // (B*S, 2048) bf16 roped, pre-scaled
    const ushort_t* __restrict__ Qn,   // (B*S, 2048) bf16 q_new, pre-scaled
    const ushort_t* __restrict__ Kcat, // (B, NKV, 2048, 128) bf16
    const ushort_t* __restrict__ Vt,   // (B, NKV, 128, 2048) bf16
    ushort_t* __restrict__ attnb)      // (B*S, 2048) bf16
{
  const int tid = threadIdx.x;
  const int lane = tid & 63;
  const int w = tid >> 6;
  const int fr = lane & 15;
  const int fq = lane >> 4;
  const int blk = blockIdx.x;
  const int qt = blk & 15;
  const int h  = (blk >> 4) & 15;
  const int b  = blk >> 8;
  const int kvh = h >> 2;
  const int q0 = qt * 64 + w * 16;
  const int qrow = q0 + fr;                   // this lane's query (S^T col)
  const int kperm = (fr >> 2) * 8 + (fr & 3); // permuted K-row index

  const ushort_t* Kb = Kcat + dsz(b * NKVc + kvh) * 2048 * HDc;
  const ushort_t* Vb = Vt   + dsz(b * NKVc + kvh) * HDc * 2048;

  float m = -1e30f, l = 0.f;
  f32x4 ot[8];
  #pragma unroll
  for (int dt = 0; dt < 8; ++dt) ot[dt] = (f32x4){0.f, 0.f, 0.f, 0.f};

  for (int phase = 0; phase < 2; ++phase) {
    const ushort_t* Qp = phase ? Qr : Qn;
    bf16x8 qf[4];
    {
      const ushort_t* qsrc = Qp + dsz(b * Sc + qrow) * (NHc * HDc) + h * HDc;
      #pragma unroll
      for (int c = 0; c < 4; ++c) qf[c] = *(const bf16x8*)&qsrc[c * 32 + fq * 8];
    }
    const int kb0 = phase ? 1024 : 0;
    const int ntiles = phase ? ((q0 + 16 + 31) >> 5) : 32;

    for (int t = 0; t < ntiles; ++t) {
      const int k0 = t * 32;
      // K fragments (permuted rows: tile0 -> key kperm, tile1 -> key kperm+4)
      bf16x8 ka0[4], ka1[4], va[8];
      const ushort_t* kr0 = Kb + dsz(kb0 + k0 + kperm) * HDc;
      const ushort_t* kr1 = kr0 + 4 * HDc;
      #pragma unroll
      for (int c = 0; c < 4; ++c) {
        ka0[c] = *(const bf16x8*)&kr0[c * 32 + fq * 8];
        ka1[c] = *(const bf16x8*)&kr1[c * 32 + fq * 8];
      }
      #pragma unroll
      for (int dt = 0; dt < 8; ++dt)
        va[dt] = *(const bf16x8*)&Vb[dsz(dt * 16 + fr) * 2048 + kb0 + k0 + fq * 8];

      // S^T = K * Q^T   (rows = permuted keys, cols = queries)
      f32x4 s0 = (f32x4){0.f, 0.f, 0.f, 0.f};
      f32x4 s1 = (f32x4){0.f, 0.f, 0.f, 0.f};
      #pragma unroll
      for (int c = 0; c < 4; ++c)
        s0 = __builtin_amdgcn_mfma_f32_16x16x32_bf16(ka0[c], qf[c], s0, 0, 0, 0);
      #pragma unroll
      for (int c = 0; c < 4; ++c)
        s1 = __builtin_amdgcn_mfma_f32_16x16x32_bf16(ka1[c], qf[c], s1, 0, 0, 0);

      // lane holds keys: s0[j] -> k0 + fq*8 + j ; s1[j] -> k0 + fq*8 + 4 + j
      if (phase) {
        #pragma unroll
        for (int j = 0; j < 4; ++j) {
          s0[j] = (k0 + fq * 8 + j     > qrow) ? -1e30f : s0[j];
          s1[j] = (k0 + fq * 8 + 4 + j > qrow) ? -1e30f : s1[j];
        }
      }
      float tmax = fmaxf(fmaxf(fmaxf(s0[0], s0[1]), fmaxf(s0[2], s0[3])),
                         fmaxf(fmaxf(s1[0], s1[1]), fmaxf(s1[2], s1[3])));
      tmax = fmaxf(tmax, __shfl_xor(tmax, 16));
      tmax = fmaxf(tmax, __shfl_xor(tmax, 32));

      if (__any(tmax > m + 8.f)) {              // defer-max (T13)
        float mnew = fmaxf(m, tmax);
        float corr = exp2f(m - mnew);
        l *= corr;
        #pragma unroll
        for (int dt = 0; dt < 8; ++dt) {
          ot[dt][0] *= corr; ot[dt][1] *= corr;
          ot[dt][2] *= corr; ot[dt][3] *= corr;
        }
        m = mnew;
      }
      float ps = 0.f;
      bf16x8 pb;
      #pragma unroll
      for (int j = 0; j < 4; ++j) {
        float p = exp2f(s0[j] - m); ps += p; pb[j] = (__bf16)p;
      }
      #pragma unroll
      for (int j = 0; j < 4; ++j) {
        float p = exp2f(s1[j] - m); ps += p; pb[j + 4] = (__bf16)p;
      }
      l += ps;

      // O^T += V^T * P^T
      #pragma unroll
      for (int dt = 0; dt < 8; ++dt)
        ot[dt] = __builtin_amdgcn_mfma_f32_16x16x32_bf16(va[dt], pb, ot[dt], 0, 0, 0);
    }
  }

  l += __shfl_xor(l, 16);
  l += __shfl_xor(l, 32);
  const float linv = 1.f / l;
  ushort_t* obase = attnb + dsz(b * Sc + qrow) * (NHc * HDc) + h * HDc;
  #pragma unroll
  for (int dt = 0; dt < 8; ++dt) {
    ushort4 o4;
    o4.x = f2bf(ot[dt][0] * linv);
    o4.y = f2bf(ot[dt][1] * linv);
    o4.z = f2bf(ot[dt][2] * linv);
    o4.w = f2bf(ot[dt][3] * linv);
    *(ushort4*)&obase[dt * 16 + fq * 4] = o4;
  }
}

// ---------------------------------------------------------------------------
// Launch
// ---------------------------------------------------------------------------
extern "C" void kernel_launch(void* const* d_in, const int* in_sizes, int n_in,
                              void* d_out, int out_size, void* d_ws, size_t ws_size,
                              hipStream_t stream)
{
  const float* x    = (const float*)d_in[0];
  const int*   pos  = (const int*)d_in[2];
  const float* kbk  = (const float*)d_in[3];
  const float* kbv  = (const float*)d_in[4];
  const float* Wq   = (const float*)d_in[5];
  const float* Wqn  = (const float*)d_in[6];
  const float* Wk   = (const float*)d_in[7];
  const float* Wv   = (const float*)d_in[8];
  const float* Wo   = (const float*)d_in[9];
  float* out = (float*)d_out;

  const int MR = Bc * Sc;              // 2048
  const size_t M4 = (size_t)MR * 2048; // 4M
  const size_t M1 = (size_t)MR * 512;  // 1M

  float* ws  = (float*)d_ws;
  float* q   = ws;               // 4M f
  float* qn  = q   + M4;         // 4M f
  float* kkv = qn  + M4;         // 1M f
  float* vkv = kkv + M1;         // 1M f
  ushort_t* bfb  = (ushort_t*)(vkv + M1);
  ushort_t* xb   = bfb;                // 4M u
  ushort_t* Wqb  = xb   + M4;          // 4M u
  ushort_t* Wqnb = Wqb  + M4;          // 4M u
  ushort_t* Wkb  = Wqnb + M4;          // 1M u
  ushort_t* Wvb  = Wkb  + M1;          // 1M u
  ushort_t* Wob  = Wvb  + M1;          // 4M u
  // aliases (regions dead by the time these are written):
  ushort_t* Qrb  = Wqb;                       // after q-GEMM
  ushort_t* Qnb  = Wqnb;                      // after qn-GEMM
  ushort_t* Kcat = (ushort_t*)q;              // 2M u, after rope_q reads q
  ushort_t* Vtb  = Kcat + (size_t)2 * 1024 * 1024;  // 2M u (still in q region)
  ushort_t* attnb = xb;                       // after all x-GEMMs

  dim3 blk(256);
  // conversions
  f32_to_bf16<<<(int)(M4 / 4 / 256), blk, 0, stream>>>(x,   xb,   (int)(M4 / 4));
  f32_to_bf16<<<(int)(M4 / 4 / 256), blk, 0, stream>>>(Wq,  Wqb,  (int)(M4 / 4));
  f32_to_bf16<<<(int)(M4 / 4 / 256), blk, 0, stream>>>(Wqn, Wqnb, (int)(M4 / 4));
  f32_to_bf16<<<(int)(M1 / 4 / 256), blk, 0, stream>>>(Wk,  Wkb,  (int)(M1 / 4));
  f32_to_bf16<<<(int)(M1 / 4 / 256), blk, 0, stream>>>(Wv,  Wvb,  (int)(M1 / 4));
  f32_to_bf16<<<(int)(M4 / 4 / 256), blk, 0, stream>>>(Wo,  Wob,  (int)(M4 / 4));

  // projections
  gemm_bt_bf16<<<dim3(16, 16), blk, 0, stream>>>(xb, Wqb,  q,   MR, 2048, Hc);
  gemm_bt_bf16<<<dim3(16, 16), blk, 0, stream>>>(xb, Wqnb, qn,  MR, 2048, Hc);
  gemm_bt_bf16<<<dim3(4,  16), blk, 0, stream>>>(xb, Wkb,  kkv, MR, 512,  Hc);
  gemm_bt_bf16<<<dim3(4,  16), blk, 0, stream>>>(xb, Wvb,  vkv, MR, 512,  Hc);

  // q/qn -> bf16 (pre-scaled); MUST precede Kcat/Vt writes (they alias q region)
  rope_q_bf16<<<(int)(M4 / 2 / 256), blk, 0, stream>>>(q, pos, Qrb);
  f32_to_bf16_s<<<(int)(M4 / 4 / 256), blk, 0, stream>>>(qn, Qnb, (int)(M4 / 4), QSCALE);

  // K/V rearrangement
  kb_kcat<<<1024, blk, 0, stream>>>(kbk, Kcat);
  rope_k_kcat<<<2048, blk, 0, stream>>>(kkv, pos, Kcat);
  vt_build<<<dim3(64, 4, 8), blk, 0, stream>>>(kbv, vkv, Vtb);

  // attention
  attn_mfma<<<512, blk, 0, stream>>>(Qrb, Qnb, Kcat, Vtb, attnb);

  // output projection
  gemm_bt_bf16<<<dim3(16, 16), blk, 0, stream>>>(attnb, Wob, out, MR, 2048, Hc);
}

// Round 4
// 355.299 us; speedup vs baseline: 6.2773x; 1.4240x over previous
//
#include <hip/hip_runtime.h>

// Problem constants
#define Bc   2
#define Sc   1024
#define Hc   2048
#define NHc  16
#define NKVc 4
#define HDc  128
#define KBc  1024
#define NREPc 4

typedef unsigned short ushort_t;
typedef unsigned int uint32;
typedef __attribute__((ext_vector_type(8))) __bf16 bf16x8;
typedef __attribute__((ext_vector_type(4))) float f32x4;

static __device__ __forceinline__ size_t dsz(int x) { return (size_t)x; }

static __device__ __forceinline__ ushort_t f2bf(float f) {
  uint32 u = __float_as_uint(f);
  u += 0x7fffu + ((u >> 16) & 1u);        // round-to-nearest-even
  return (ushort_t)(u >> 16);
}
static __device__ __forceinline__ float bf2f(ushort_t u) {
  return __uint_as_float(((uint32)u) << 16);
}

#define ROPE_INV 0.14391156831212787f   // ln(10000)/64
#define QSCALE   (0.08838834764831845f * 1.4426950408889634f)  // scale*log2e

// ---------------------------------------------------------------------------
// Fused fp32 -> bf16 conversion of all 6 inputs (one dispatch).
// f4-unit segments: x[0,F) Wq[F,2F) Wqn[2F,3F) Wk[3F,3.25F) Wv[3.25F,3.5F) Wo[3.5F,4.5F)
// ---------------------------------------------------------------------------
#define FSEG 1048576
__global__ void conv_all(const float* __restrict__ x,  const float* __restrict__ Wq,
                         const float* __restrict__ Wqn, const float* __restrict__ Wk,
                         const float* __restrict__ Wv,  const float* __restrict__ Wo,
                         ushort_t* xb, ushort_t* Wqb, ushort_t* Wqnb,
                         ushort_t* Wkb, ushort_t* Wvb, ushort_t* Wob)
{
  int i = blockIdx.x * 256 + threadIdx.x;      // f4 index, < 4.5*FSEG
  const float* s; ushort_t* d; int off;
  if      (i <     FSEG)            { s = x;   d = xb;   off = i; }
  else if (i < 2 * FSEG)            { s = Wq;  d = Wqb;  off = i - FSEG; }
  else if (i < 3 * FSEG)            { s = Wqn; d = Wqnb; off = i - 2 * FSEG; }
  else if (i < 3 * FSEG + FSEG / 4) { s = Wk;  d = Wkb;  off = i - 3 * FSEG; }
  else if (i < 3 * FSEG + FSEG / 2) { s = Wv;  d = Wvb;  off = i - 3 * FSEG - FSEG / 4; }
  else                              { s = Wo;  d = Wob;  off = i - 3 * FSEG - FSEG / 2; }
  float4 v = ((const float4*)s)[off];
  ushort4 o;
  o.x = f2bf(v.x); o.y = f2bf(v.y); o.z = f2bf(v.z); o.w = f2bf(v.w);
  ((ushort4*)d)[off] = o;
}

// ---------------------------------------------------------------------------
// global_load_lds helper
// ---------------------------------------------------------------------------
#define GL16(gsrc, ldst)                                                \
  __builtin_amdgcn_global_load_lds(                                     \
      (const __attribute__((address_space(1))) void*)(gsrc),            \
      (__attribute__((address_space(3))) void*)(ldst), 16, 0, 0)

// ---------------------------------------------------------------------------
// Fused projection GEMM (one dispatch, 640 blocks): C = xb * W^T for
// {Wq->qb, Wqn->qnb(*QSCALE), Wk->kkvb, Wv->vkvb}, bf16 outputs.
// m97 structure: 128x128 tile, 4 waves 2x2, BK=32, global_load_lds w16.
// ---------------------------------------------------------------------------
__global__ __launch_bounds__(256) void gemm_proj(
    const ushort_t* __restrict__ A,    // xb [2048][2048]
    const ushort_t* __restrict__ Wqb,  const ushort_t* __restrict__ Wqnb,
    const ushort_t* __restrict__ Wkb,  const ushort_t* __restrict__ Wvb,
    ushort_t* __restrict__ qb, ushort_t* __restrict__ qnb,
    ushort_t* __restrict__ kkvb, ushort_t* __restrict__ vkvb)
{
  __shared__ ushort_t sA[128 * 32];
  __shared__ ushort_t sB[128 * 32];

  const int K = Hc;                    // 2048
  const int bx = blockIdx.x;
  const ushort_t* Bseg; ushort_t* Cseg; int segN, colseg; float scale;
  if      (bx < 16) { Bseg = Wqb;  Cseg = qb;   segN = 2048; colseg = bx * 128;        scale = 1.f; }
  else if (bx < 32) { Bseg = Wqnb; Cseg = qnb;  segN = 2048; colseg = (bx - 16) * 128; scale = QSCALE; }
  else if (bx < 36) { Bseg = Wkb;  Cseg = kkvb; segN = 512;  colseg = (bx - 32) * 128; scale = 1.f; }
  else              { Bseg = Wvb;  Cseg = vkvb; segN = 512;  colseg = (bx - 36) * 128; scale = 1.f; }

  const int tid  = threadIdx.x;
  const int lane = tid & 63;
  const int wid  = tid >> 6;
  const int wr   = wid >> 1;
  const int wc   = wid & 1;
  const int row0 = blockIdx.y * 128;
  const int fr = lane & 15;
  const int fq = lane >> 4;

  f32x4 acc[4][4];
  #pragma unroll
  for (int m = 0; m < 4; ++m)
    #pragma unroll
    for (int n = 0; n < 4; ++n) acc[m][n] = (f32x4){0.f, 0.f, 0.f, 0.f};

  const int rS = tid >> 2;
  const int kg = (tid & 3) * 8;
  const ushort_t* Asrc0 = A + dsz(row0 + rS) * K + kg;
  const ushort_t* Asrc1 = A + dsz(row0 + 64 + rS) * K + kg;
  const ushort_t* Bsrc0 = Bseg + dsz(colseg + rS) * K + kg;
  const ushort_t* Bsrc1 = Bseg + dsz(colseg + 64 + rS) * K + kg;
  char* ldsA0 = (char*)sA + tid * 16;
  char* ldsA1 = (char*)sA + 4096 + tid * 16;
  char* ldsB0 = (char*)sB + tid * 16;
  char* ldsB1 = (char*)sB + 4096 + tid * 16;

  for (int k0 = 0; k0 < K; k0 += 32) {
    GL16(Asrc0 + k0, ldsA0);
    GL16(Asrc1 + k0, ldsA1);
    GL16(Bsrc0 + k0, ldsB0);
    GL16(Bsrc1 + k0, ldsB1);
    __syncthreads();

    bf16x8 a[4], b[4];
    #pragma unroll
    for (int m = 0; m < 4; ++m)
      a[m] = *(const bf16x8*)&sA[(wr * 64 + m * 16 + fr) * 32 + fq * 8];
    #pragma unroll
    for (int n = 0; n < 4; ++n)
      b[n] = *(const bf16x8*)&sB[(wc * 64 + n * 16 + fr) * 32 + fq * 8];
    #pragma unroll
    for (int m = 0; m < 4; ++m)
      #pragma unroll
      for (int n = 0; n < 4; ++n)
        acc[m][n] = __builtin_amdgcn_mfma_f32_16x16x32_bf16(a[m], b[n], acc[m][n], 0, 0, 0);
    __syncthreads();
  }

  #pragma unroll
  for (int m = 0; m < 4; ++m)
    #pragma unroll
    for (int n = 0; n < 4; ++n)
      #pragma unroll
      for (int j = 0; j < 4; ++j)
        Cseg[dsz(row0 + wr * 64 + m * 16 + fq * 4 + j) * segN +
             colseg + wc * 64 + n * 16 + fr] = f2bf(acc[m][n][j] * scale);
}

// ---------------------------------------------------------------------------
// Generic bf16 GEMM with f32 output (for the final Wo projection).
// ---------------------------------------------------------------------------
__global__ __launch_bounds__(256) void gemm_bt_bf16(
    const ushort_t* __restrict__ A, const ushort_t* __restrict__ B,
    float* __restrict__ C, int M, int N, int K)
{
  __shared__ ushort_t sA[128 * 32];
  __shared__ ushort_t sB[128 * 32];

  const int tid  = threadIdx.x;
  const int lane = tid & 63;
  const int wid  = tid >> 6;
  const int wr   = wid >> 1;
  const int wc   = wid & 1;
  const int row0 = blockIdx.y * 128;
  const int col0 = blockIdx.x * 128;
  const int fr = lane & 15;
  const int fq = lane >> 4;

  f32x4 acc[4][4];
  #pragma unroll
  for (int m = 0; m < 4; ++m)
    #pragma unroll
    for (int n = 0; n < 4; ++n) acc[m][n] = (f32x4){0.f, 0.f, 0.f, 0.f};

  const int rS = tid >> 2;
  const int kg = (tid & 3) * 8;
  const ushort_t* Asrc0 = A + dsz(row0 + rS) * K + kg;
  const ushort_t* Asrc1 = A + dsz(row0 + 64 + rS) * K + kg;
  const ushort_t* Bsrc0 = B + dsz(col0 + rS) * K + kg;
  const ushort_t* Bsrc1 = B + dsz(col0 + 64 + rS) * K + kg;
  char* ldsA0 = (char*)sA + tid * 16;
  char* ldsA1 = (char*)sA + 4096 + tid * 16;
  char* ldsB0 = (char*)sB + tid * 16;
  char* ldsB1 = (char*)sB + 4096 + tid * 16;

  for (int k0 = 0; k0 < K; k0 += 32) {
    GL16(Asrc0 + k0, ldsA0);
    GL16(Asrc1 + k0, ldsA1);
    GL16(Bsrc0 + k0, ldsB0);
    GL16(Bsrc1 + k0, ldsB1);
    __syncthreads();

    bf16x8 a[4], b[4];
    #pragma unroll
    for (int m = 0; m < 4; ++m)
      a[m] = *(const bf16x8*)&sA[(wr * 64 + m * 16 + fr) * 32 + fq * 8];
    #pragma unroll
    for (int n = 0; n < 4; ++n)
      b[n] = *(const bf16x8*)&sB[(wc * 64 + n * 16 + fr) * 32 + fq * 8];
    #pragma unroll
    for (int m = 0; m < 4; ++m)
      #pragma unroll
      for (int n = 0; n < 4; ++n)
        acc[m][n] = __builtin_amdgcn_mfma_f32_16x16x32_bf16(a[m], b[n], acc[m][n], 0, 0, 0);
    __syncthreads();
  }

  #pragma unroll
  for (int m = 0; m < 4; ++m)
    #pragma unroll
    for (int n = 0; n < 4; ++n)
      #pragma unroll
      for (int j = 0; j < 4; ++j)
        C[dsz(row0 + wr * 64 + m * 16 + fq * 4 + j) * N +
          col0 + wc * 64 + n * 16 + fr] = acc[m][n][j];
}

// ---------------------------------------------------------------------------
// RoPE in-place on bf16 qb, folds in QSCALE. Thread owns (r,h,j): dims j, j+64.
// ---------------------------------------------------------------------------
__global__ void rope_q_ip(ushort_t* __restrict__ qb, const int* __restrict__ pos)
{
  int idx = blockIdx.x * blockDim.x + threadIdx.x;   // 2M
  int j = idx & 63;
  int h = (idx >> 6) & 15;
  int r = idx >> 10;
  float p = (float)pos[r];
  float f = p * expf(-(float)j * ROPE_INV);
  float c = cosf(f), s = sinf(f);
  ushort_t* d = qb + dsz(r) * (NHc * HDc) + h * HDc;
  float x1 = bf2f(d[j]), x2 = bf2f(d[j + 64]);
  d[j]      = f2bf((x1 * c - x2 * s) * QSCALE);
  d[j + 64] = f2bf((x2 * c + x1 * s) * QSCALE);
}

// RoPE self-k (bf16 in) -> Kcat rows 1024..2047
__global__ void rope_k_kcat(const ushort_t* __restrict__ kkvb, const int* __restrict__ pos,
                            ushort_t* __restrict__ Kcat)
{
  int idx = blockIdx.x * blockDim.x + threadIdx.x;   // 512K
  int j = idx & 63;
  int kvh = (idx >> 6) & 3;
  int s = (idx >> 8) & 1023;
  int b = idx >> 18;
  float p = (float)pos[b * Sc + s];
  float f = p * expf(-(float)j * ROPE_INV);
  float c = cosf(f), sn = sinf(f);
  const ushort_t* src = kkvb + dsz(b * Sc + s) * (NKVc * HDc) + kvh * HDc;
  ushort_t* dst = Kcat + (dsz(b * NKVc + kvh) * 2048 + 1024 + s) * HDc;
  float x1 = bf2f(src[j]), x2 = bf2f(src[j + 64]);
  dst[j]      = f2bf(x1 * c - x2 * sn);
  dst[j + 64] = f2bf(x2 * c + x1 * sn);
}

// kb_keys fp32 -> Kcat rows 0..1023 bf16
__global__ void kb_kcat(const float* __restrict__ src, ushort_t* __restrict__ Kcat)
{
  int i = blockIdx.x * blockDim.x + threadIdx.x;     // 262144
  int d4 = i & 31;
  int kvh = (i >> 5) & 3;
  int k = (i >> 7) & 1023;
  int b = i >> 17;
  float4 v = *(const float4*)&src[dsz(b * KBc + k) * (NKVc * HDc) + kvh * HDc + d4 * 4];
  ushort4 o;
  o.x = f2bf(v.x); o.y = f2bf(v.y); o.z = f2bf(v.z); o.w = f2bf(v.w);
  *(ushort4*)&Kcat[(dsz(b * NKVc + kvh) * 2048 + k) * HDc + d4 * 4] = o;
}

// Build Vt[b][kvh][128][2048] from kb_values (f32, cols 0..1023) + vkvb (bf16, 1024..)
__global__ __launch_bounds__(256) void vt_build(const float* __restrict__ kbv,
                                                const ushort_t* __restrict__ vkvb,
                                                ushort_t* __restrict__ Vt)
{
  __shared__ float sT[32][33];
  const int k0 = blockIdx.x * 32;
  const int d0 = blockIdx.y * 32;
  const int bk = blockIdx.z;
  const int b = bk >> 2, kvh = bk & 3;
  const int tid = threadIdx.x;

  #pragma unroll
  for (int t = 0; t < 4; ++t) {
    int li = tid + t * 256;
    int kk = li >> 5, dl = li & 31;
    int kg = k0 + kk;
    float v = (kg < 1024)
      ? kbv[dsz(b * KBc + kg) * (NKVc * HDc) + kvh * HDc + d0 + dl]
      : bf2f(vkvb[dsz(b * Sc + kg - 1024) * (NKVc * HDc) + kvh * HDc + d0 + dl]);
    sT[kk][dl] = v;
  }
  __syncthreads();
  #pragma unroll
  for (int t = 0; t < 4; ++t) {
    int li = tid + t * 256;
    int dl = li >> 5, kk = li & 31;
    Vt[(dsz(b * NKVc + kvh) * HDc + d0 + dl) * 2048 + k0 + kk] = f2bf(sT[kk][dl]);
  }
}

// ---------------------------------------------------------------------------
// Attention: intra-block flash-decoding. Block = (b,h,16 q), 4 waves split the
// key stream into contiguous chunks; partials merged in LDS by wave 0.
// ---------------------------------------------------------------------------
template<bool MASKED>
static __device__ __forceinline__ void attn_range(
    int t_lo, int t_hi,
    const ushort_t* __restrict__ Qsrc,   // lane's q row (+h*128)
    const ushort_t* __restrict__ Kb, const ushort_t* __restrict__ Vb,
    int qrow, int kperm, int fr, int fq,
    float& m, float& l, f32x4 (&ot)[8])
{
  if (t_lo >= t_hi) return;
  bf16x8 qf[4];
  #pragma unroll
  for (int c = 0; c < 4; ++c) qf[c] = *(const bf16x8*)&Qsrc[c * 32 + fq * 8];

  for (int t = t_lo; t < t_hi; ++t) {
    const ushort_t* kr0 = Kb + dsz(t * 32 + kperm) * HDc;
    const ushort_t* kr1 = kr0 + 4 * HDc;
    bf16x8 ka0[4], ka1[4], va[8];
    #pragma unroll
    for (int c = 0; c < 4; ++c) {
      ka0[c] = *(const bf16x8*)&kr0[c * 32 + fq * 8];
      ka1[c] = *(const bf16x8*)&kr1[c * 32 + fq * 8];
    }
    #pragma unroll
    for (int dt = 0; dt < 8; ++dt)
      va[dt] = *(const bf16x8*)&Vb[dsz(dt * 16 + fr) * 2048 + t * 32 + fq * 8];

    f32x4 s0 = (f32x4){0.f, 0.f, 0.f, 0.f};
    f32x4 s1 = (f32x4){0.f, 0.f, 0.f, 0.f};
    #pragma unroll
    for (int c = 0; c < 4; ++c)
      s0 = __builtin_amdgcn_mfma_f32_16x16x32_bf16(ka0[c], qf[c], s0, 0, 0, 0);
    #pragma unroll
    for (int c = 0; c < 4; ++c)
      s1 = __builtin_amdgcn_mfma_f32_16x16x32_bf16(ka1[c], qf[c], s1, 0, 0, 0);

    if (MASKED) {
      #pragma unroll
      for (int j = 0; j < 4; ++j) {
        s0[j] = (t * 32 + fq * 8 + j     - 1024 > qrow) ? -1e30f : s0[j];
        s1[j] = (t * 32 + fq * 8 + 4 + j - 1024 > qrow) ? -1e30f : s1[j];
      }
    }
    float tmax = fmaxf(fmaxf(fmaxf(s0[0], s0[1]), fmaxf(s0[2], s0[3])),
                       fmaxf(fmaxf(s1[0], s1[1]), fmaxf(s1[2], s1[3])));
    tmax = fmaxf(tmax, __shfl_xor(tmax, 16));
    tmax = fmaxf(tmax, __shfl_xor(tmax, 32));

    if (__any(tmax > m + 8.f)) {                 // defer-max (T13)
      float mnew = fmaxf(m, tmax);
      float corr = exp2f(m - mnew);
      l *= corr;
      #pragma unroll
      for (int dt = 0; dt < 8; ++dt) {
        ot[dt][0] *= corr; ot[dt][1] *= corr;
        ot[dt][2] *= corr; ot[dt][3] *= corr;
      }
      m = mnew;
    }
    float ps = 0.f;
    bf16x8 pb;
    #pragma unroll
    for (int j = 0; j < 4; ++j) { float p = exp2f(s0[j] - m); ps += p; pb[j] = (__bf16)p; }
    #pragma unroll
    for (int j = 0; j < 4; ++j) { float p = exp2f(s1[j] - m); ps += p; pb[j + 4] = (__bf16)p; }
    l += ps;

    #pragma unroll
    for (int dt = 0; dt < 8; ++dt)
      ot[dt] = __builtin_amdgcn_mfma_f32_16x16x32_bf16(va[dt], pb, ot[dt], 0, 0, 0);
  }
}

__global__ __launch_bounds__(256) void attn_mfma2(
    const ushort_t* __restrict__ Qr,   // roped q (pre-scaled), (B*S, 2048)
    const ushort_t* __restrict__ Qn,   // q_new (pre-scaled), (B*S, 2048)
    const ushort_t* __restrict__ Kcat, // (B, NKV, 2048, 128)
    const ushort_t* __restrict__ Vt,   // (B, NKV, 128, 2048)
    ushort_t* __restrict__ attnb)      // (B*S, 2048)
{
  __shared__ float sO[3][128][17];
  __shared__ float sM[3][16];
  __shared__ float sL[3][16];

  const int tid = threadIdx.x;
  const int lane = tid & 63;
  const int w = tid >> 6;
  const int fr = lane & 15;
  const int fq = lane >> 4;
  const int blk = blockIdx.x;
  const int qt = blk & 63;
  const int h  = (blk >> 6) & 15;
  const int b  = blk >> 10;
  const int kvh = h >> 2;
  const int q0 = qt * 16;
  const int qrow = q0 + fr;
  const int kperm = (fr >> 2) * 8 + (fr & 3);

  const ushort_t* Kb = Kcat + dsz(b * NKVc + kvh) * 2048 * HDc;
  const ushort_t* Vb = Vt   + dsz(b * NKVc + kvh) * HDc * 2048;
  const ushort_t* Qnrow = Qn + dsz(b * Sc + qrow) * (NHc * HDc) + h * HDc;
  const ushort_t* Qrrow = Qr + dsz(b * Sc + qrow) * (NHc * HDc) + h * HDc;

  // valid concat keys = 1024 + q0 + 16; tiles of 32
  const int ntiles = (q0 + 1071) >> 5;          // 33..64
  const int cbase = ntiles >> 2, crem = ntiles & 3;
  const int t_lo = w * cbase + (w < crem ? w : crem);
  const int t_hi = t_lo + cbase + (w < crem ? 1 : 0);
  const int hi0 = t_hi < 32 ? t_hi : 32;
  const int lo1 = t_lo > 32 ? t_lo : 32;

  float m = -1e30f, l = 0.f;
  f32x4 ot[8];
  #pragma unroll
  for (int dt = 0; dt < 8; ++dt) ot[dt] = (f32x4){0.f, 0.f, 0.f, 0.f};

  attn_range<false>(t_lo, hi0, Qnrow, Kb, Vb, qrow, kperm, fr, fq, m, l, ot);
  attn_range<true >(lo1, t_hi, Qrrow, Kb, Vb, qrow, kperm, fr, fq, m, l, ot);

  // full per-query l (sum over fq lanes)
  l += __shfl_xor(l, 16);
  l += __shfl_xor(l, 32);

  if (w > 0) {
    #pragma unroll
    for (int dt = 0; dt < 8; ++dt)
      #pragma unroll
      for (int j = 0; j < 4; ++j)
        sO[w - 1][dt * 16 + fq * 4 + j][fr] = ot[dt][j];
    if (lane < 16) { sM[w - 1][lane] = m; sL[w - 1][lane] = l; }
  }
  __syncthreads();

  if (w == 0) {
    float mw[3], lw[3];
    float M = m;
    #pragma unroll
    for (int ww = 0; ww < 3; ++ww) {
      mw[ww] = sM[ww][fr]; lw[ww] = sL[ww][fr];
      M = fmaxf(M, mw[ww]);
    }
    float sc0 = exp2f(m - M);
    float L = l * sc0;
    float sc[3];
    #pragma unroll
    for (int ww = 0; ww < 3; ++ww) { sc[ww] = exp2f(mw[ww] - M); L += lw[ww] * sc[ww]; }
    const float Linv = 1.f / L;
    ushort_t* obase = attnb + dsz(b * Sc + qrow) * (NHc * HDc) + h * HDc;
    #pragma unroll
    for (int dt = 0; dt < 8; ++dt) {
      ushort_t o4a[4];
      #pragma unroll
      for (int j = 0; j < 4; ++j) {
        float v = ot[dt][j] * sc0;
        #pragma unroll
        for (int ww = 0; ww < 3; ++ww)
          v += sO[ww][dt * 16 + fq * 4 + j][fr] * sc[ww];
        o4a[j] = f2bf(v * Linv);
      }
      *(ushort4*)&obase[dt * 16 + fq * 4] = *(ushort4*)o4a;
    }
  }
}

// ---------------------------------------------------------------------------
// Launch
// ---------------------------------------------------------------------------
extern "C" void kernel_launch(void* const* d_in, const int* in_sizes, int n_in,
                              void* d_out, int out_size, void* d_ws, size_t ws_size,
                              hipStream_t stream)
{
  const float* x    = (const float*)d_in[0];
  const int*   pos  = (const int*)d_in[2];
  const float* kbk  = (const float*)d_in[3];
  const float* kbv  = (const float*)d_in[4];
  const float* Wq   = (const float*)d_in[5];
  const float* Wqn  = (const float*)d_in[6];
  const float* Wk   = (const float*)d_in[7];
  const float* Wv   = (const float*)d_in[8];
  const float* Wo   = (const float*)d_in[9];
  float* out = (float*)d_out;

  const int MR = Bc * Sc;              // 2048
  const size_t MU = 1048576;

  ushort_t* U = (ushort_t*)d_ws;
  ushort_t* xb    = U;                 // 4M u
  ushort_t* Wqb   = U + 4  * MU;       // 4M
  ushort_t* Wqnb  = U + 8  * MU;       // 4M
  ushort_t* Wkb   = U + 12 * MU;       // 1M
  ushort_t* Wvb   = U + 13 * MU;       // 1M
  ushort_t* Wob   = U + 14 * MU;       // 4M
  ushort_t* qb    = U + 18 * MU;       // 4M (roped in-place -> Qr)
  ushort_t* qnb   = U + 22 * MU;       // 4M (pre-scaled)
  ushort_t* kkvb  = U + 26 * MU;       // 1M
  ushort_t* vkvb  = U + 27 * MU;       // 1M
  ushort_t* Kcat  = U + 28 * MU;       // 2M
  ushort_t* Vt    = U + 30 * MU;       // 2M
  ushort_t* attnb = U + 32 * MU;       // 4M  -> total 36M u = 72 MB

  dim3 blk(256);

  // 1. all input conversions (one dispatch)
  conv_all<<<18432, blk, 0, stream>>>(x, Wq, Wqn, Wk, Wv, Wo,
                                      xb, Wqb, Wqnb, Wkb, Wvb, Wob);
  // 2. fused projections -> bf16 (qnb pre-scaled)
  gemm_proj<<<dim3(40, 16), blk, 0, stream>>>(xb, Wqb, Wqnb, Wkb, Wvb,
                                              qb, qnb, kkvb, vkvb);
  // 3. RoPE q in-place (+QSCALE)
  rope_q_ip<<<8192, blk, 0, stream>>>(qb, pos);
  // 4-6. K/V rearrangement
  kb_kcat<<<1024, blk, 0, stream>>>(kbk, Kcat);
  rope_k_kcat<<<2048, blk, 0, stream>>>(kkvb, pos, Kcat);
  vt_build<<<dim3(64, 4, 8), blk, 0, stream>>>(kbv, vkvb, Vt);
  // 7. attention (2048 blocks, intra-block KV-split)
  attn_mfma2<<<2048, blk, 0, stream>>>(qb, qnb, Kcat, Vt, attnb);
  // 8. output projection
  gemm_bt_bf16<<<dim3(16, 16), blk, 0, stream>>>(attnb, Wob, out, MR, 2048, Hc);
}

// Round 5
// 224.512 us; speedup vs baseline: 9.9341x; 1.5825x over previous
//
#include <hip/hip_runtime.h>

// Problem constants
#define Bc   2
#define Sc   1024
#define Hc   2048
#define NHc  16
#define NKVc 4
#define HDc  128
#define KBc  1024
#define NREPc 4

typedef unsigned short ushort_t;
typedef unsigned int uint32;
typedef __attribute__((ext_vector_type(8))) __bf16 bf16x8;
typedef __attribute__((ext_vector_type(4))) float f32x4;

static __device__ __forceinline__ size_t dsz(int x) { return (size_t)x; }

static __device__ __forceinline__ ushort_t f2bf(float f) {
  uint32 u = __float_as_uint(f);
  u += 0x7fffu + ((u >> 16) & 1u);        // round-to-nearest-even
  return (ushort_t)(u >> 16);
}
static __device__ __forceinline__ float bf2f(ushort_t u) {
  return __uint_as_float(((uint32)u) << 16);
}

#define ROPE_INV 0.14391156831212787f   // ln(10000)/64
#define QSCALE   (0.08838834764831845f * 1.4426950408889634f)  // scale*log2e

// ---------------------------------------------------------------------------
// Fused fp32 -> bf16 conversion of all 6 inputs (one dispatch).
// ---------------------------------------------------------------------------
#define FSEG 1048576
__global__ void conv_all(const float* __restrict__ x,  const float* __restrict__ Wq,
                         const float* __restrict__ Wqn, const float* __restrict__ Wk,
                         const float* __restrict__ Wv,  const float* __restrict__ Wo,
                         ushort_t* xb, ushort_t* Wqb, ushort_t* Wqnb,
                         ushort_t* Wkb, ushort_t* Wvb, ushort_t* Wob)
{
  int i = blockIdx.x * 256 + threadIdx.x;      // f4 index, < 4.5*FSEG
  const float* s; ushort_t* d; int off;
  if      (i <     FSEG)            { s = x;   d = xb;   off = i; }
  else if (i < 2 * FSEG)            { s = Wq;  d = Wqb;  off = i - FSEG; }
  else if (i < 3 * FSEG)            { s = Wqn; d = Wqnb; off = i - 2 * FSEG; }
  else if (i < 3 * FSEG + FSEG / 4) { s = Wk;  d = Wkb;  off = i - 3 * FSEG; }
  else if (i < 3 * FSEG + FSEG / 2) { s = Wv;  d = Wvb;  off = i - 3 * FSEG - FSEG / 4; }
  else                              { s = Wo;  d = Wob;  off = i - 3 * FSEG - FSEG / 2; }
  float4 v = ((const float4*)s)[off];
  ushort4 o;
  o.x = f2bf(v.x); o.y = f2bf(v.y); o.z = f2bf(v.z); o.w = f2bf(v.w);
  ((ushort4*)d)[off] = o;
}

// ---------------------------------------------------------------------------
// global_load_lds helper
// ---------------------------------------------------------------------------
#define GL16(gsrc, ldst)                                                \
  __builtin_amdgcn_global_load_lds(                                     \
      (const __attribute__((address_space(1))) void*)(gsrc),            \
      (__attribute__((address_space(3))) void*)(ldst), 16, 0, 0)

// ---------------------------------------------------------------------------
// Fused projection GEMM (one dispatch, 640 blocks): C = xb * W^T for
// {Wq->qb, Wqn->qnb(*QSCALE), Wk->kkvb, Wv->vkvb}, bf16 outputs.
// ---------------------------------------------------------------------------
__global__ __launch_bounds__(256) void gemm_proj(
    const ushort_t* __restrict__ A,    // xb [2048][2048]
    const ushort_t* __restrict__ Wqb,  const ushort_t* __restrict__ Wqnb,
    const ushort_t* __restrict__ Wkb,  const ushort_t* __restrict__ Wvb,
    ushort_t* __restrict__ qb, ushort_t* __restrict__ qnb,
    ushort_t* __restrict__ kkvb, ushort_t* __restrict__ vkvb)
{
  __shared__ ushort_t sA[128 * 32];
  __shared__ ushort_t sB[128 * 32];

  const int K = Hc;                    // 2048
  const int bx = blockIdx.x;
  const ushort_t* Bseg; ushort_t* Cseg; int segN, colseg; float scale;
  if      (bx < 16) { Bseg = Wqb;  Cseg = qb;   segN = 2048; colseg = bx * 128;        scale = 1.f; }
  else if (bx < 32) { Bseg = Wqnb; Cseg = qnb;  segN = 2048; colseg = (bx - 16) * 128; scale = QSCALE; }
  else if (bx < 36) { Bseg = Wkb;  Cseg = kkvb; segN = 512;  colseg = (bx - 32) * 128; scale = 1.f; }
  else              { Bseg = Wvb;  Cseg = vkvb; segN = 512;  colseg = (bx - 36) * 128; scale = 1.f; }

  const int tid  = threadIdx.x;
  const int lane = tid & 63;
  const int wid  = tid >> 6;
  const int wr   = wid >> 1;
  const int wc   = wid & 1;
  const int row0 = blockIdx.y * 128;
  const int fr = lane & 15;
  const int fq = lane >> 4;

  f32x4 acc[4][4];
  #pragma unroll
  for (int m = 0; m < 4; ++m)
    #pragma unroll
    for (int n = 0; n < 4; ++n) acc[m][n] = (f32x4){0.f, 0.f, 0.f, 0.f};

  const int rS = tid >> 2;
  const int kg = (tid & 3) * 8;
  const ushort_t* Asrc0 = A + dsz(row0 + rS) * K + kg;
  const ushort_t* Asrc1 = A + dsz(row0 + 64 + rS) * K + kg;
  const ushort_t* Bsrc0 = Bseg + dsz(colseg + rS) * K + kg;
  const ushort_t* Bsrc1 = Bseg + dsz(colseg + 64 + rS) * K + kg;
  char* ldsA0 = (char*)sA + tid * 16;
  char* ldsA1 = (char*)sA + 4096 + tid * 16;
  char* ldsB0 = (char*)sB + tid * 16;
  char* ldsB1 = (char*)sB + 4096 + tid * 16;

  for (int k0 = 0; k0 < K; k0 += 32) {
    GL16(Asrc0 + k0, ldsA0);
    GL16(Asrc1 + k0, ldsA1);
    GL16(Bsrc0 + k0, ldsB0);
    GL16(Bsrc1 + k0, ldsB1);
    __syncthreads();

    bf16x8 a[4], b[4];
    #pragma unroll
    for (int m = 0; m < 4; ++m)
      a[m] = *(const bf16x8*)&sA[(wr * 64 + m * 16 + fr) * 32 + fq * 8];
    #pragma unroll
    for (int n = 0; n < 4; ++n)
      b[n] = *(const bf16x8*)&sB[(wc * 64 + n * 16 + fr) * 32 + fq * 8];
    #pragma unroll
    for (int m = 0; m < 4; ++m)
      #pragma unroll
      for (int n = 0; n < 4; ++n)
        acc[m][n] = __builtin_amdgcn_mfma_f32_16x16x32_bf16(a[m], b[n], acc[m][n], 0, 0, 0);
    __syncthreads();
  }

  #pragma unroll
  for (int m = 0; m < 4; ++m)
    #pragma unroll
    for (int n = 0; n < 4; ++n)
      #pragma unroll
      for (int j = 0; j < 4; ++j)
        Cseg[dsz(row0 + wr * 64 + m * 16 + fq * 4 + j) * segN +
             colseg + wc * 64 + n * 16 + fr] = f2bf(acc[m][n][j] * scale);
}

// ---------------------------------------------------------------------------
// Generic bf16 GEMM with f32 output (final Wo projection).
// ---------------------------------------------------------------------------
__global__ __launch_bounds__(256) void gemm_bt_bf16(
    const ushort_t* __restrict__ A, const ushort_t* __restrict__ B,
    float* __restrict__ C, int M, int N, int K)
{
  __shared__ ushort_t sA[128 * 32];
  __shared__ ushort_t sB[128 * 32];

  const int tid  = threadIdx.x;
  const int lane = tid & 63;
  const int wid  = tid >> 6;
  const int wr   = wid >> 1;
  const int wc   = wid & 1;
  const int row0 = blockIdx.y * 128;
  const int col0 = blockIdx.x * 128;
  const int fr = lane & 15;
  const int fq = lane >> 4;

  f32x4 acc[4][4];
  #pragma unroll
  for (int m = 0; m < 4; ++m)
    #pragma unroll
    for (int n = 0; n < 4; ++n) acc[m][n] = (f32x4){0.f, 0.f, 0.f, 0.f};

  const int rS = tid >> 2;
  const int kg = (tid & 3) * 8;
  const ushort_t* Asrc0 = A + dsz(row0 + rS) * K + kg;
  const ushort_t* Asrc1 = A + dsz(row0 + 64 + rS) * K + kg;
  const ushort_t* Bsrc0 = B + dsz(col0 + rS) * K + kg;
  const ushort_t* Bsrc1 = B + dsz(col0 + 64 + rS) * K + kg;
  char* ldsA0 = (char*)sA + tid * 16;
  char* ldsA1 = (char*)sA + 4096 + tid * 16;
  char* ldsB0 = (char*)sB + tid * 16;
  char* ldsB1 = (char*)sB + 4096 + tid * 16;

  for (int k0 = 0; k0 < K; k0 += 32) {
    GL16(Asrc0 + k0, ldsA0);
    GL16(Asrc1 + k0, ldsA1);
    GL16(Bsrc0 + k0, ldsB0);
    GL16(Bsrc1 + k0, ldsB1);
    __syncthreads();

    bf16x8 a[4], b[4];
    #pragma unroll
    for (int m = 0; m < 4; ++m)
      a[m] = *(const bf16x8*)&sA[(wr * 64 + m * 16 + fr) * 32 + fq * 8];
    #pragma unroll
    for (int n = 0; n < 4; ++n)
      b[n] = *(const bf16x8*)&sB[(wc * 64 + n * 16 + fr) * 32 + fq * 8];
    #pragma unroll
    for (int m = 0; m < 4; ++m)
      #pragma unroll
      for (int n = 0; n < 4; ++n)
        acc[m][n] = __builtin_amdgcn_mfma_f32_16x16x32_bf16(a[m], b[n], acc[m][n], 0, 0, 0);
    __syncthreads();
  }

  #pragma unroll
  for (int m = 0; m < 4; ++m)
    #pragma unroll
    for (int n = 0; n < 4; ++n)
      #pragma unroll
      for (int j = 0; j < 4; ++j)
        C[dsz(row0 + wr * 64 + m * 16 + fq * 4 + j) * N +
          col0 + wc * 64 + n * 16 + fr] = acc[m][n][j];
}

// ---------------------------------------------------------------------------
// RoPE in-place on bf16 qb, folds in QSCALE.
// ---------------------------------------------------------------------------
__global__ void rope_q_ip(ushort_t* __restrict__ qb, const int* __restrict__ pos)
{
  int idx = blockIdx.x * blockDim.x + threadIdx.x;   // 2M
  int j = idx & 63;
  int h = (idx >> 6) & 15;
  int r = idx >> 10;
  float p = (float)pos[r];
  float f = p * expf(-(float)j * ROPE_INV);
  float c = cosf(f), s = sinf(f);
  ushort_t* d = qb + dsz(r) * (NHc * HDc) + h * HDc;
  float x1 = bf2f(d[j]), x2 = bf2f(d[j + 64]);
  d[j]      = f2bf((x1 * c - x2 * s) * QSCALE);
  d[j + 64] = f2bf((x2 * c + x1 * s) * QSCALE);
}

// RoPE self-k (bf16 in) -> Kcat rows 1024..2047
__global__ void rope_k_kcat(const ushort_t* __restrict__ kkvb, const int* __restrict__ pos,
                            ushort_t* __restrict__ Kcat)
{
  int idx = blockIdx.x * blockDim.x + threadIdx.x;   // 512K
  int j = idx & 63;
  int kvh = (idx >> 6) & 3;
  int s = (idx >> 8) & 1023;
  int b = idx >> 18;
  float p = (float)pos[b * Sc + s];
  float f = p * expf(-(float)j * ROPE_INV);
  float c = cosf(f), sn = sinf(f);
  const ushort_t* src = kkvb + dsz(b * Sc + s) * (NKVc * HDc) + kvh * HDc;
  ushort_t* dst = Kcat + (dsz(b * NKVc + kvh) * 2048 + 1024 + s) * HDc;
  float x1 = bf2f(src[j]), x2 = bf2f(src[j + 64]);
  dst[j]      = f2bf(x1 * c - x2 * sn);
  dst[j + 64] = f2bf(x2 * c + x1 * sn);
}

// kb_keys fp32 -> Kcat rows 0..1023 bf16
__global__ void kb_kcat(const float* __restrict__ src, ushort_t* __restrict__ Kcat)
{
  int i = blockIdx.x * blockDim.x + threadIdx.x;     // 262144
  int d4 = i & 31;
  int kvh = (i >> 5) & 3;
  int k = (i >> 7) & 1023;
  int b = i >> 17;
  float4 v = *(const float4*)&src[dsz(b * KBc + k) * (NKVc * HDc) + kvh * HDc + d4 * 4];
  ushort4 o;
  o.x = f2bf(v.x); o.y = f2bf(v.y); o.z = f2bf(v.z); o.w = f2bf(v.w);
  *(ushort4*)&Kcat[(dsz(b * NKVc + kvh) * 2048 + k) * HDc + d4 * 4] = o;
}

// Build Vt[b][kvh][128][2048] from kb_values (f32) + vkvb (bf16)
__global__ __launch_bounds__(256) void vt_build(const float* __restrict__ kbv,
                                                const ushort_t* __restrict__ vkvb,
                                                ushort_t* __restrict__ Vt)
{
  __shared__ float sT[32][33];
  const int k0 = blockIdx.x * 32;
  const int d0 = blockIdx.y * 32;
  const int bk = blockIdx.z;
  const int b = bk >> 2, kvh = bk & 3;
  const int tid = threadIdx.x;

  #pragma unroll
  for (int t = 0; t < 4; ++t) {
    int li = tid + t * 256;
    int kk = li >> 5, dl = li & 31;
    int kg = k0 + kk;
    float v = (kg < 1024)
      ? kbv[dsz(b * KBc + kg) * (NKVc * HDc) + kvh * HDc + d0 + dl]
      : bf2f(vkvb[dsz(b * Sc + kg - 1024) * (NKVc * HDc) + kvh * HDc + d0 + dl]);
    sT[kk][dl] = v;
  }
  __syncthreads();
  #pragma unroll
  for (int t = 0; t < 4; ++t) {
    int li = tid + t * 256;
    int dl = li >> 5, kk = li & 31;
    Vt[(dsz(b * NKVc + kvh) * HDc + d0 + dl) * 2048 + k0 + kk] = f2bf(sT[kk][dl]);
  }
}

// ---------------------------------------------------------------------------
// Attention v3: LDS-staged, double-buffered flash attention.
// Block = (b, h, 64 q), 4 waves x 16 q each (no merge). Per 32-key tile:
// stage K (8KB, XOR-swizzled rows) + Vt slice (8KB, linear) via global_load_lds,
// 2-phase pipeline (stage t+1 while computing t), fragments via ds_read_b128.
// ---------------------------------------------------------------------------
__global__ __launch_bounds__(256, 2) void attn_mfma3(
    const ushort_t* __restrict__ Qr,   // roped q (pre-scaled), (B*S, 2048)
    const ushort_t* __restrict__ Qn,   // q_new (pre-scaled), (B*S, 2048)
    const ushort_t* __restrict__ Kcat, // (B, NKV, 2048, 128)
    const ushort_t* __restrict__ Vt,   // (B, NKV, 128, 2048)
    ushort_t* __restrict__ attnb)      // (B*S, 2048)
{
  __shared__ ushort_t sK[2][32 * 128];   // [buf][key-row][128 dims], rows swizzled
  __shared__ ushort_t sV[2][128 * 32];   // [buf][dim-row][32 keys], linear

  const int tid = threadIdx.x;
  const int lane = tid & 63;
  const int w = tid >> 6;
  const int fr = lane & 15;
  const int fq = lane >> 4;
  const int blk = blockIdx.x;
  const int qt = blk & 15;
  const int h  = (blk >> 4) & 15;
  const int b  = blk >> 8;
  const int kvh = h >> 2;
  const int qrow = qt * 64 + w * 16 + fr;
  const int kperm = ((fr >> 2) << 3) + (fr & 3);   // permuted K row
  const int kswzU = (fr & 4) << 3;                 // ushort-index XOR for K reads

  const ushort_t* Kb = Kcat + dsz(b * NKVc + kvh) * 2048 * HDc;
  const ushort_t* Vb = Vt   + dsz(b * NKVc + kvh) * HDc * 2048;

  // staging thread-constant byte offsets
  const int kmask = (tid & 128) >> 1;                              // (row&8)<<3
  const int kOff0 = (tid >> 4) * 256 + (((tid & 15) * 16) ^ kmask);
  const int vOff0 = (tid >> 2) * 4096 + (tid & 3) * 16;

  // Q fragments (both phases) up front
  bf16x8 qn_f[4], qr_f[4];
  {
    const ushort_t* qn_row = Qn + dsz(b * Sc + qrow) * (NHc * HDc) + h * HDc;
    const ushort_t* qr_row = Qr + dsz(b * Sc + qrow) * (NHc * HDc) + h * HDc;
    #pragma unroll
    for (int c = 0; c < 4; ++c) {
      qn_f[c] = *(const bf16x8*)&qn_row[c * 32 + fq * 8];
      qr_f[c] = *(const bf16x8*)&qr_row[c * 32 + fq * 8];
    }
  }

  const int ntiles = (1119 + qt * 64) >> 5;    // 1024 + qt*64 + 64 keys, /32

  float m = -1e30f, l = 0.f;
  f32x4 ot[8];
  #pragma unroll
  for (int dt = 0; dt < 8; ++dt) ot[dt] = (f32x4){0.f, 0.f, 0.f, 0.f};

#define STAGE(bi, t)                                                        \
  {                                                                         \
    const char* kg8 = (const char*)Kb + (size_t)(t) * 8192;                 \
    const char* vg8 = (const char*)Vb + (size_t)(t) * 64;                   \
    GL16(kg8 + kOff0,        (char*)&sK[bi][0] + tid * 16);                 \
    GL16(kg8 + kOff0 + 4096, (char*)&sK[bi][0] + 4096 + tid * 16);          \
    GL16(vg8 + vOff0,          (char*)&sV[bi][0] + tid * 16);               \
    GL16(vg8 + vOff0 + 262144, (char*)&sV[bi][0] + 4096 + tid * 16);        \
  }

  STAGE(0, 0);
  __syncthreads();

  for (int t = 0; t < ntiles; ++t) {
    const int cur = t & 1;
    if (t + 1 < ntiles) STAGE(cur ^ 1, t + 1);

    // fragments from LDS
    bf16x8 ka0[4], ka1[4], va[8];
    #pragma unroll
    for (int c = 0; c < 4; ++c) {
      ka0[c] = *(const bf16x8*)&sK[cur][kperm * 128 + ((c * 32 + fq * 8) ^ kswzU)];
      ka1[c] = *(const bf16x8*)&sK[cur][(kperm + 4) * 128 + ((c * 32 + fq * 8) ^ kswzU)];
    }
    #pragma unroll
    for (int dt = 0; dt < 8; ++dt)
      va[dt] = *(const bf16x8*)&sV[cur][(dt * 16 + fr) * 32 + fq * 8];

    f32x4 s0 = (f32x4){0.f, 0.f, 0.f, 0.f};
    f32x4 s1 = (f32x4){0.f, 0.f, 0.f, 0.f};
    const int kb = t * 32;
    if (kb < 1024) {          // KB phase: q_new, no mask
      #pragma unroll
      for (int c = 0; c < 4; ++c)
        s0 = __builtin_amdgcn_mfma_f32_16x16x32_bf16(ka0[c], qn_f[c], s0, 0, 0, 0);
      #pragma unroll
      for (int c = 0; c < 4; ++c)
        s1 = __builtin_amdgcn_mfma_f32_16x16x32_bf16(ka1[c], qn_f[c], s1, 0, 0, 0);
    } else {                  // self phase: roped q, causal mask
      #pragma unroll
      for (int c = 0; c < 4; ++c)
        s0 = __builtin_amdgcn_mfma_f32_16x16x32_bf16(ka0[c], qr_f[c], s0, 0, 0, 0);
      #pragma unroll
      for (int c = 0; c < 4; ++c)
        s1 = __builtin_amdgcn_mfma_f32_16x16x32_bf16(ka1[c], qr_f[c], s1, 0, 0, 0);
      #pragma unroll
      for (int j = 0; j < 4; ++j) {
        s0[j] = (kb + fq * 8 + j     - 1024 > qrow) ? -1e30f : s0[j];
        s1[j] = (kb + fq * 8 + 4 + j - 1024 > qrow) ? -1e30f : s1[j];
      }
    }

    float tmax = fmaxf(fmaxf(fmaxf(s0[0], s0[1]), fmaxf(s0[2], s0[3])),
                       fmaxf(fmaxf(s1[0], s1[1]), fmaxf(s1[2], s1[3])));
    tmax = fmaxf(tmax, __shfl_xor(tmax, 16));
    tmax = fmaxf(tmax, __shfl_xor(tmax, 32));

    if (__any(tmax > m + 8.f)) {                 // defer-max (T13)
      float mnew = fmaxf(m, tmax);
      float corr = exp2f(m - mnew);
      l *= corr;
      #pragma unroll
      for (int dt = 0; dt < 8; ++dt) {
        ot[dt][0] *= corr; ot[dt][1] *= corr;
        ot[dt][2] *= corr; ot[dt][3] *= corr;
      }
      m = mnew;
    }
    float ps = 0.f;
    bf16x8 pb;
    #pragma unroll
    for (int j = 0; j < 4; ++j) { float p = exp2f(s0[j] - m); ps += p; pb[j] = (__bf16)p; }
    #pragma unroll
    for (int j = 0; j < 4; ++j) { float p = exp2f(s1[j] - m); ps += p; pb[j + 4] = (__bf16)p; }
    l += ps;

    #pragma unroll
    for (int dt = 0; dt < 8; ++dt)
      ot[dt] = __builtin_amdgcn_mfma_f32_16x16x32_bf16(va[dt], pb, ot[dt], 0, 0, 0);

    __syncthreads();   // drains this iter's STAGE loads; buffers swap safely
  }
#undef STAGE

  l += __shfl_xor(l, 16);
  l += __shfl_xor(l, 32);
  const float linv = 1.f / l;
  ushort_t* obase = attnb + dsz(b * Sc + qrow) * (NHc * HDc) + h * HDc;
  #pragma unroll
  for (int dt = 0; dt < 8; ++dt) {
    ushort_t o4a[4];
    #pragma unroll
    for (int j = 0; j < 4; ++j) o4a[j] = f2bf(ot[dt][j] * linv);
    *(ushort4*)&obase[dt * 16 + fq * 4] = *(ushort4*)o4a;
  }
}

// ---------------------------------------------------------------------------
// Launch
// ---------------------------------------------------------------------------
extern "C" void kernel_launch(void* const* d_in, const int* in_sizes, int n_in,
                              void* d_out, int out_size, void* d_ws, size_t ws_size,
                              hipStream_t stream)
{
  const float* x    = (const float*)d_in[0];
  const int*   pos  = (const int*)d_in[2];
  const float* kbk  = (const float*)d_in[3];
  const float* kbv  = (const float*)d_in[4];
  const float* Wq   = (const float*)d_in[5];
  const float* Wqn  = (const float*)d_in[6];
  const float* Wk   = (const float*)d_in[7];
  const float* Wv   = (const float*)d_in[8];
  const float* Wo   = (const float*)d_in[9];
  float* out = (float*)d_out;

  const int MR = Bc * Sc;              // 2048
  const size_t MU = 1048576;

  ushort_t* U = (ushort_t*)d_ws;
  ushort_t* xb    = U;                 // 4M u
  ushort_t* Wqb   = U + 4  * MU;       // 4M
  ushort_t* Wqnb  = U + 8  * MU;       // 4M
  ushort_t* Wkb   = U + 12 * MU;       // 1M
  ushort_t* Wvb   = U + 13 * MU;       // 1M
  ushort_t* Wob   = U + 14 * MU;       // 4M
  ushort_t* qb    = U + 18 * MU;       // 4M (roped in-place -> Qr)
  ushort_t* qnb   = U + 22 * MU;       // 4M (pre-scaled)
  ushort_t* kkvb  = U + 26 * MU;       // 1M
  ushort_t* vkvb  = U + 27 * MU;       // 1M
  ushort_t* Kcat  = U + 28 * MU;       // 2M
  ushort_t* Vt    = U + 30 * MU;       // 2M
  ushort_t* attnb = U + 32 * MU;       // 4M  -> total 36M u = 72 MB

  dim3 blk(256);

  conv_all<<<18432, blk, 0, stream>>>(x, Wq, Wqn, Wk, Wv, Wo,
                                      xb, Wqb, Wqnb, Wkb, Wvb, Wob);
  gemm_proj<<<dim3(40, 16), blk, 0, stream>>>(xb, Wqb, Wqnb, Wkb, Wvb,
                                              qb, qnb, kkvb, vkvb);
  rope_q_ip<<<8192, blk, 0, stream>>>(qb, pos);
  kb_kcat<<<1024, blk, 0, stream>>>(kbk, Kcat);
  rope_k_kcat<<<2048, blk, 0, stream>>>(kkvb, pos, Kcat);
  vt_build<<<dim3(64, 4, 8), blk, 0, stream>>>(kbv, vkvb, Vt);
  // attention: (b,h,64q) blocks, LDS-staged double-buffered
  attn_mfma3<<<512, blk, 0, stream>>>(qb, qnb, Kcat, Vt, attnb);
  gemm_bt_bf16<<<dim3(16, 16), blk, 0, stream>>>(attnb, Wob, out, MR, 2048, Hc);
}